// Round 12
// baseline (174.706 us; speedup 1.0000x reference)
//
#include <hip/hip_runtime.h>
#include <math.h>

#define NN 8192
#define KDIM 256
#define DD 64
#define NB 4096
#define NBLK 256
#define NTHR 512
#define RPB 32           // rows per block
#define CH 32            // sorted elements per chunk
#define NCH 256          // chunks
#define LRALPHA 0.2f

__device__ __forceinline__ unsigned f2k(float f) {
    unsigned u = __float_as_uint(f);
    return u ^ ((u >> 31) ? 0xFFFFFFFFu : 0x80000000u);
}
__device__ __forceinline__ float k2f(unsigned k) {
    return __uint_as_float((k & 0x80000000u) ? (k ^ 0x80000000u) : ~k);
}
__device__ __forceinline__ unsigned bucket_of(unsigned key, unsigned kmin, float scale) {
    unsigned d = key - kmin;
    unsigned b = (unsigned)((float)d * scale);
    return b > (NB - 1) ? (NB - 1) : b;
}

// ---------------- K1: Wh = h@W (+ Wh1, Wh2). 256 blocks x 512, 4 rows/wave ----------------
__global__ __launch_bounds__(NTHR) void k_gemm(
    const float* __restrict__ h, const float* __restrict__ W,
    const float* __restrict__ a,
    float* __restrict__ Wh, float* __restrict__ Wh1, float* __restrict__ Wh2)
{
    const int t = threadIdx.x, wv = t >> 6, lane = t & 63;
    const int r0 = blockIdx.x * RPB + wv * 4;
    float acc0 = 0.f, acc1 = 0.f, acc2 = 0.f, acc3 = 0.f;
    #pragma unroll 2
    for (int k4 = 0; k4 < KDIM / 4; ++k4) {
        float w0 = W[(4 * k4 + 0) * DD + lane];
        float w1 = W[(4 * k4 + 1) * DD + lane];
        float w2 = W[(4 * k4 + 2) * DD + lane];
        float w3 = W[(4 * k4 + 3) * DD + lane];
        float4 h0 = *(const float4*)(h + (size_t)(r0 + 0) * KDIM + 4 * k4);
        float4 h1 = *(const float4*)(h + (size_t)(r0 + 1) * KDIM + 4 * k4);
        float4 h2 = *(const float4*)(h + (size_t)(r0 + 2) * KDIM + 4 * k4);
        float4 h3 = *(const float4*)(h + (size_t)(r0 + 3) * KDIM + 4 * k4);
        acc0 = fmaf(h0.x, w0, acc0); acc0 = fmaf(h0.y, w1, acc0);
        acc0 = fmaf(h0.z, w2, acc0); acc0 = fmaf(h0.w, w3, acc0);
        acc1 = fmaf(h1.x, w0, acc1); acc1 = fmaf(h1.y, w1, acc1);
        acc1 = fmaf(h1.z, w2, acc1); acc1 = fmaf(h1.w, w3, acc1);
        acc2 = fmaf(h2.x, w0, acc2); acc2 = fmaf(h2.y, w1, acc2);
        acc2 = fmaf(h2.z, w2, acc2); acc2 = fmaf(h2.w, w3, acc2);
        acc3 = fmaf(h3.x, w0, acc3); acc3 = fmaf(h3.y, w1, acc3);
        acc3 = fmaf(h3.z, w2, acc3); acc3 = fmaf(h3.w, w3, acc3);
    }
    float a1 = a[lane], a2 = a[DD + lane];
    float accs[4] = {acc0, acc1, acc2, acc3};
    #pragma unroll
    for (int i = 0; i < 4; ++i) {
        int row = r0 + i;
        Wh[(size_t)row * DD + lane] = accs[i];
        float r1 = accs[i] * a1, r2 = accs[i] * a2;
        #pragma unroll
        for (int off = 32; off > 0; off >>= 1) {
            r1 += __shfl_xor(r1, off, 64);
            r2 += __shfl_xor(r2, off, 64);
        }
        if (lane == 0) { Wh1[row] = r1; Wh2[row] = r2; }
    }
}

// ---------------- K2: redundant minmax+hist+scan per block; scatter own 32 rows ----------------
__global__ __launch_bounds__(NTHR) void k_scatter(
    const float* __restrict__ Wh, const float* __restrict__ Wh2,
    float* __restrict__ svp, float* __restrict__ sg,
    int* __restrict__ bstart_g, float* __restrict__ meta, int* __restrict__ cnt)
{
    __shared__ int      ls_bstart[NB + 1];
    __shared__ unsigned ls_ra[8], ls_rb[8];
    __shared__ int      ls_wsum[8];
    __shared__ float    ls_M2, ls_scale;
    __shared__ unsigned ls_kmin;

    const int t = threadIdx.x, bid = blockIdx.x;
    const int wv = t >> 6, lane = t & 63;
    const int rowBase = bid * RPB;

    for (int i = t; i < NB; i += NTHR) ls_bstart[i] = 0;
    float v16[16];
    {
        const float4* w4p = (const float4*)Wh2;
        #pragma unroll
        for (int q = 0; q < 4; ++q) {
            float4 x4 = w4p[t * 4 + q];          // plain cached vectorized
            v16[4 * q + 0] = x4.x; v16[4 * q + 1] = x4.y;
            v16[4 * q + 2] = x4.z; v16[4 * q + 3] = x4.w;
        }
        unsigned lmin = 0xFFFFFFFFu, lmax = 0u;
        #pragma unroll
        for (int q = 0; q < 16; ++q) {
            unsigned k = f2k(v16[q]);
            lmin = min(lmin, k); lmax = max(lmax, k);
        }
        #pragma unroll
        for (int off = 32; off > 0; off >>= 1) {
            lmin = min(lmin, (unsigned)__shfl_xor((int)lmin, off, 64));
            lmax = max(lmax, (unsigned)__shfl_xor((int)lmax, off, 64));
        }
        if (lane == 0) { ls_ra[wv] = lmin; ls_rb[wv] = lmax; }
    }
    __syncthreads();
    if (t == 0) {
        unsigned mn = ls_ra[0], mx = ls_rb[0];
        for (int i = 1; i < 8; ++i) { mn = min(mn, ls_ra[i]); mx = max(mx, ls_rb[i]); }
        ls_kmin = mn;
        ls_scale = (float)NB / ((float)(mx - mn) + 1.0f);
        ls_M2 = k2f(mx);
    }
    __syncthreads();
    const unsigned kmin = ls_kmin;
    const float scale = ls_scale;
    const float M2 = ls_M2;

    #pragma unroll
    for (int q = 0; q < 16; ++q)
        atomicAdd(&ls_bstart[bucket_of(f2k(v16[q]), kmin, scale)], 1);
    __syncthreads();
    {
        int s[8]; int tot = 0;
        #pragma unroll
        for (int j = 0; j < 8; ++j) { s[j] = ls_bstart[8 * t + j]; tot += s[j]; }
        int x = tot;
        #pragma unroll
        for (int off = 1; off < 64; off <<= 1) {
            int y = __shfl_up(x, off, 64);
            if (lane >= off) x += y;
        }
        if (lane == 63) ls_wsum[wv] = x;
        __syncthreads();
        int woff = 0;
        for (int w2 = 0; w2 < wv; ++w2) woff += ls_wsum[w2];
        int acc = woff + x - tot;
        #pragma unroll
        for (int j = 0; j < 8; ++j) { ls_bstart[8 * t + j] = acc; acc += s[j]; }
        if (t == 0) ls_bstart[NB] = NN;
    }
    __syncthreads();
    // block 0 persists bstart + meta for K5 (all blocks computed identical copies)
    if (bid == 0) {
        for (int i = t; i < NB + 1; i += NTHR) bstart_g[i] = ls_bstart[i];
        if (t == 0) {
            meta[0] = M2;
            meta[1] = __uint_as_float(kmin);
            meta[2] = scale;
        }
    }
    // scatter own 32 rows: concurrent cursor RMWs on lanes 0-3, rows via plain cached I/O
    {
        int posl = 0;
        if (lane < 4) {
            float x = Wh2[rowBase + wv * 4 + lane];
            unsigned b = bucket_of(f2k(x), kmin, scale);
            posl = ls_bstart[b] + atomicAdd(&cnt[b], 1);
        }
        #pragma unroll
        for (int i = 0; i < 4; ++i) {
            int row = rowBase + wv * 4 + i;
            float x = Wh2[row];                              // broadcast cached load
            float g = Wh[(size_t)row * DD + lane];           // coalesced cached load
            int pos = __shfl(posl, i, 64);
            sg[(size_t)pos * DD + lane] = g;
            if (lane == 0) {
                svp[4 * pos + 0] = x;
                svp[4 * pos + 1] = expf(LRALPHA * (x - M2)); // wn <= 1
                svp[4 * pos + 2] = expf(x - M2);             // wp <= 1
                svp[4 * pos + 3] = 0.f;
            }
        }
    }
}

// ---------------- K3: chunk sums (chunk = bid) ----------------
__global__ __launch_bounds__(NTHR) void k_chunksum(
    const float* __restrict__ svp, const float* __restrict__ sg,
    float* __restrict__ cs_neg, float* __restrict__ cs_pos,
    float* __restrict__ cs_sn, float* __restrict__ cs_sp)
{
    __shared__ float ls_cs[8][2 * DD];
    __shared__ float ls_css[16];
    const int t = threadIdx.x, bid = blockIdx.x;
    const int wv = t >> 6, lane = t & 63;
    int base = bid * CH + wv * 4;
    float an = 0.f, ap = 0.f, sn = 0.f, sp = 0.f;
    #pragma unroll
    for (int kk = 0; kk < 4; ++kk) {
        int k = base + kk;
        float4 q = ((const float4*)svp)[k];
        float g = sg[(size_t)k * DD + lane];
        an = fmaf(q.y, g, an); ap = fmaf(q.z, g, ap);
        sn += q.y; sp += q.z;
    }
    ls_cs[wv][lane] = an; ls_cs[wv][DD + lane] = ap;
    if (lane == 0) { ls_css[wv] = sn; ls_css[8 + wv] = sp; }
    __syncthreads();
    if (wv == 0) {
        float s = 0.f;
        #pragma unroll
        for (int w2 = 0; w2 < 8; ++w2) s += ls_cs[w2][lane];
        cs_neg[bid * DD + lane] = s;
        if (lane == 0) { float ss = 0.f; for (int w2 = 0; w2 < 8; ++w2) ss += ls_css[w2]; cs_sn[bid] = ss; }
    } else if (wv == 1) {
        float s = 0.f;
        #pragma unroll
        for (int w2 = 0; w2 < 8; ++w2) s += ls_cs[w2][DD + lane];
        cs_pos[bid * DD + lane] = s;
        if (lane == 0) { float ss = 0.f; for (int w2 = 0; w2 < 8; ++w2) ss += ls_css[8 + w2]; cs_sp[bid] = ss; }
    }
}

// ---------------- K4: scans of the 256 chunk sums (3 blocks) ----------------
__global__ __launch_bounds__(NTHR) void k_scan(
    const float* __restrict__ cs_neg, const float* __restrict__ cs_pos,
    const float* __restrict__ cs_sn, const float* __restrict__ cs_sp,
    float* __restrict__ PN, float* __restrict__ SP,
    float* __restrict__ PNs, float* __restrict__ SPs)
{
    __shared__ float ls_cs[8][2 * DD];
    const int t = threadIdx.x, bid = blockIdx.x;
    const int wv = t >> 6, lane = t & 63;
    if (bid == 0) {
        const int c0 = wv * 32;
        float v[32];
        #pragma unroll
        for (int j = 0; j < 32; ++j) v[j] = cs_neg[(c0 + j) * DD + lane];
        float tot = 0.f;
        #pragma unroll
        for (int j = 0; j < 32; ++j) tot += v[j];
        ls_cs[wv][lane] = tot;
        __syncthreads();
        float acc = 0.f;
        for (int w2 = 0; w2 < wv; ++w2) acc += ls_cs[w2][lane];
        #pragma unroll
        for (int j = 0; j < 32; ++j) { PN[(c0 + j) * DD + lane] = acc; acc += v[j]; }
        if (wv == 7) PN[NCH * DD + lane] = acc;
    } else if (bid == 1) {
        const int c0 = wv * 32;
        float v[32];
        #pragma unroll
        for (int j = 0; j < 32; ++j) v[j] = cs_pos[(c0 + j) * DD + lane];
        float tot = 0.f;
        #pragma unroll
        for (int j = 0; j < 32; ++j) tot += v[j];
        ls_cs[wv][lane] = tot;
        __syncthreads();
        float acc = 0.f;
        for (int w2 = wv + 1; w2 < 8; ++w2) acc += ls_cs[w2][lane];   // FIX: was [DD+lane] (uninitialized)
        #pragma unroll
        for (int j = 31; j >= 0; --j) { acc += v[j]; SP[(c0 + j) * DD + lane] = acc; }
        if (wv == 7) SP[NCH * DD + lane] = 0.f;
    } else {
        if (wv == 0) {          // scalar prefix
            float s[4];
            #pragma unroll
            for (int j = 0; j < 4; ++j) s[j] = cs_sn[4 * lane + j];
            float tot = s[0] + s[1] + s[2] + s[3];
            float x = tot;
            #pragma unroll
            for (int off = 1; off < 64; off <<= 1) {
                float y = __shfl_up(x, off, 64);
                if (lane >= off) x += y;
            }
            float acc = x - tot;
            #pragma unroll
            for (int j = 0; j < 4; ++j) { PNs[4 * lane + j] = acc; acc += s[j]; }
            if (lane == 63) PNs[NCH] = acc;
        } else if (wv == 1) {   // scalar suffix
            float s[4];
            #pragma unroll
            for (int j = 0; j < 4; ++j) s[j] = cs_sp[4 * lane + j];
            float tot = s[0] + s[1] + s[2] + s[3];
            float x = tot;
            #pragma unroll
            for (int off = 1; off < 64; off <<= 1) {
                float y = __shfl_down(x, off, 64);
                if (lane < 64 - off) x += y;
            }
            float acc = x - tot;   // sum over lanes > lane
            #pragma unroll
            for (int j = 3; j >= 0; --j) { acc += s[j]; SPs[4 * lane + j] = acc; }
            if (lane == 63) SPs[NCH] = 0.f;
        }
    }
}

// ---------------- K5: per-row combine + elu ----------------
__global__ __launch_bounds__(NTHR) void k_out(
    const float* __restrict__ Wh1, const float* __restrict__ svp,
    const float* __restrict__ sg,
    const float* __restrict__ PN, const float* __restrict__ SP,
    const float* __restrict__ PNs, const float* __restrict__ SPs,
    const int* __restrict__ bstart_g, const float* __restrict__ meta,
    float* __restrict__ out)
{
    __shared__ int ls_bstart[NB + 1];
    const int t = threadIdx.x, bid = blockIdx.x;
    const int wv = t >> 6, lane = t & 63;
    const int rowBase = bid * RPB;
    for (int i = t; i < NB + 1; i += NTHR) ls_bstart[i] = bstart_g[i];
    float M2 = meta[0];
    unsigned kmin = __float_as_uint(meta[1]);
    float scale = meta[2];
    __syncthreads();

    #pragma unroll
    for (int i = 0; i < 4; ++i) {
        int row = rowBase + wv * 4 + i;
        float w1 = Wh1[row];                         // broadcast cached load
        float z = w1 + M2;                           // max_j (Wh1_i + Wh2_j)
        float m = (z >= 0.f) ? z : LRALPHA * z;      // lrelu(z) = exact row max
        float c1 = expf(z - m);                      // exponent <= 0
        float c2 = expf(LRALPHA * z - m);            // exponent <= 0
        float tt = -w1;
        unsigned kt = f2k(tt);
        int p0 = 0, p1 = 0;
        if (kt >= kmin) {
            unsigned b = bucket_of(kt, kmin, scale);
            p0 = ls_bstart[b]; p1 = ls_bstart[b + 1];
        }
        int c0f = p0 >> 5, c1e = (p1 + 31) >> 5;     // CH = 32
        float nn_ = PN[c0f * DD + lane], dn_ = PNs[c0f];
        float np_ = SP[c1e * DD + lane], dp_ = SPs[c1e];
        for (int k = c0f * CH; k < c1e * CH; ++k) {
            float4 q = ((const float4*)svp)[k];      // sv, wn, wp
            float g = sg[(size_t)k * DD + lane];
            if (q.x <= tt) { nn_ = fmaf(q.y, g, nn_); dn_ += q.y; }
            else           { np_ = fmaf(q.z, g, np_); dp_ += q.z; }
        }
        float num = c2 * nn_ + c1 * np_;
        float den = c2 * dn_ + c1 * dp_;
        float r = num / den;
        out[(size_t)row * DD + lane] = (r > 0.f) ? r : expm1f(r);   // elu
    }
}

extern "C" void kernel_launch(void* const* d_in, const int* in_sizes, int n_in,
                              void* d_out, int out_size, void* d_ws, size_t ws_size,
                              hipStream_t stream)
{
    const float* h = (const float*)d_in[0];
    // d_in[1] = adj (bool, unused by the reference computation)
    const float* W = (const float*)d_in[2];
    const float* a = (const float*)d_in[3];
    float* out = (float*)d_out;
    float* ws = (float*)d_ws;

    float* Wh     = ws;                              // NN*DD
    float* Wh1    = Wh + (size_t)NN * DD;            // NN
    float* Wh2    = Wh1 + NN;                        // NN
    float* svp    = Wh2 + NN;                        // 4*NN
    float* sg     = svp + 4 * NN;                    // NN*DD
    float* cs_neg = sg + (size_t)NN * DD;            // NCH*DD
    float* cs_pos = cs_neg + NCH * DD;               // NCH*DD
    float* cs_sn  = cs_pos + NCH * DD;               // NCH
    float* cs_sp  = cs_sn + NCH;                     // NCH
    float* PN     = cs_sp + NCH;                     // (NCH+1)*DD
    float* SP     = PN + (NCH + 1) * DD;             // (NCH+1)*DD
    float* PNs    = SP + (NCH + 1) * DD;             // NCH+1 (pad 320)
    float* SPs    = PNs + 320;                       // NCH+1 (pad 320)
    float* meta   = SPs + 320;                       // 4
    int*   bstart = (int*)(meta + 4);                // NB+1 (pad)
    int*   cnt    = bstart + (NB + 64);              // NB cursors (must start 0)

    hipMemsetAsync(cnt, 0, NB * sizeof(int), stream);
    k_gemm    <<<NBLK, NTHR, 0, stream>>>(h, W, a, Wh, Wh1, Wh2);
    k_scatter <<<NBLK, NTHR, 0, stream>>>(Wh, Wh2, svp, sg, bstart, meta, cnt);
    k_chunksum<<<NBLK, NTHR, 0, stream>>>(svp, sg, cs_neg, cs_pos, cs_sn, cs_sp);
    k_scan    <<<3,    NTHR, 0, stream>>>(cs_neg, cs_pos, cs_sn, cs_sp, PN, SP, PNs, SPs);
    k_out     <<<NBLK, NTHR, 0, stream>>>(Wh1, svp, sg, PN, SP, PNs, SPs, bstart, meta, out);
}

// Round 13
// 108.556 us; speedup vs baseline: 1.6094x; 1.6094x over previous
//
#include <hip/hip_runtime.h>
#include <math.h>

#define NN 8192
#define KDIM 256
#define DD 64
#define NB 4096
#define NBLK 256
#define NTHR 512
#define RPB 32           // rows per block
#define CH 32            // sorted elements per chunk (= rows per block)
#define NCH 256          // chunks
#define LRALPHA 0.2f

__device__ __forceinline__ unsigned f2k(float f) {
    unsigned u = __float_as_uint(f);
    return u ^ ((u >> 31) ? 0xFFFFFFFFu : 0x80000000u);
}
__device__ __forceinline__ float k2f(unsigned k) {
    return __uint_as_float((k & 0x80000000u) ? (k ^ 0x80000000u) : ~k);
}
__device__ __forceinline__ unsigned bucket_of(unsigned key, unsigned kmin, float scale) {
    unsigned d = key - kmin;
    unsigned b = (unsigned)((float)d * scale);
    return b > (NB - 1) ? (NB - 1) : b;
}

// MALL-coherent bypass ops (PROVEN R7/R10): relaxed agent-scope atomics -> sc0 sc1
// L1/L2-bypass. BATCH-ISSUE loads. Do NOT use plain cached loads on cross-block data
// (R8/R9: +80us replay coherence-probe penalty). 8-byte pair variants halve counts.
__device__ __forceinline__ void  cstf(float* p, float v) { __hip_atomic_store(p, v, __ATOMIC_RELAXED, __HIP_MEMORY_SCOPE_AGENT); }
__device__ __forceinline__ float cldf(const float* p)    { return __hip_atomic_load((float*)p, __ATOMIC_RELAXED, __HIP_MEMORY_SCOPE_AGENT); }
__device__ __forceinline__ void cstf2(float* p, float x, float y) {
    union { unsigned long long u; float f[2]; } c; c.f[0] = x; c.f[1] = y;
    __hip_atomic_store((unsigned long long*)p, c.u, __ATOMIC_RELAXED, __HIP_MEMORY_SCOPE_AGENT);
}
__device__ __forceinline__ float2 cldf2(const float* p) {
    union { unsigned long long u; float2 f; } c;
    c.u = __hip_atomic_load((const unsigned long long*)p, __ATOMIC_RELAXED, __HIP_MEMORY_SCOPE_AGENT);
    return c.f;
}

// Fence-free grid barrier (proven R5/R7/R10).
__device__ __forceinline__ void gridbar(unsigned* flags, unsigned* rel, unsigned phase) {
    asm volatile("s_waitcnt vmcnt(0)" ::: "memory");
    __syncthreads();
    const int t = threadIdx.x;
    if (blockIdx.x == 0) {
        if (t == 0)
            __hip_atomic_store(&flags[0], phase, __ATOMIC_RELAXED, __HIP_MEMORY_SCOPE_AGENT);
        if (t < NBLK) {
            while (__hip_atomic_load(&flags[t], __ATOMIC_RELAXED, __HIP_MEMORY_SCOPE_AGENT) < phase)
                __builtin_amdgcn_s_sleep(1);
        }
        __syncthreads();
        if (t == 0)
            __hip_atomic_store(rel, phase, __ATOMIC_RELAXED, __HIP_MEMORY_SCOPE_AGENT);
    } else {
        if (t == 0) {
            __hip_atomic_store(&flags[blockIdx.x], phase, __ATOMIC_RELAXED, __HIP_MEMORY_SCOPE_AGENT);
            while (__hip_atomic_load(rel, __ATOMIC_RELAXED, __HIP_MEMORY_SCOPE_AGENT) < phase)
                __builtin_amdgcn_s_sleep(1);
        }
        __syncthreads();
    }
}

__global__ __launch_bounds__(NTHR, 2) void k_fused(
    const float* __restrict__ h, const float* __restrict__ W,
    const float* __restrict__ a, float* __restrict__ out,
    float* Wh2g, float* svp, float* sg,
    float* cs_neg, float* cs_pos, float* cs_sn, float* cs_sp,
    float* PN, float* SP, float* PNs, float* SPs,
    float* PNe, float* SPe, float* PNse, float* SPse,
    int* cnt, unsigned* flags, unsigned* rel)
{
    __shared__ int      ls_bstart[NB + 1];     // persists P1 -> P5
    __shared__ float    ls_wh1[RPB];
    __shared__ float    ls_wh2[RPB];
    __shared__ unsigned ls_ra[8], ls_rb[8];
    __shared__ int      ls_wsum[8];
    __shared__ float    ls_cs[8][2 * DD];      // P2 reduce / P3 scan scratch
    __shared__ float    ls_css[16];
    __shared__ float    ls_g[CH][DD];          // 8 KB: own chunk's rows (P2 -> P4)
    __shared__ float    ls_wn[CH], ls_wp[CH];  // own chunk's weights (P2 -> P4)
    __shared__ float    ls_M2, ls_scale;
    __shared__ unsigned ls_kmin;

    const int t = threadIdx.x, bid = blockIdx.x;
    const int wv = t >> 6, lane = t & 63;
    const int rowBase = bid * RPB;

    // ================= P0: GEMM; rows live in registers until scatter ======
    float myrow[4];
    {
        const int r0 = rowBase + wv * 4;
        float acc0 = 0.f, acc1 = 0.f, acc2 = 0.f, acc3 = 0.f;
        #pragma unroll 2
        for (int k4 = 0; k4 < KDIM / 4; ++k4) {
            float w0 = W[(4 * k4 + 0) * DD + lane];
            float w1 = W[(4 * k4 + 1) * DD + lane];
            float w2 = W[(4 * k4 + 2) * DD + lane];
            float w3 = W[(4 * k4 + 3) * DD + lane];
            float4 h0 = *(const float4*)(h + (size_t)(r0 + 0) * KDIM + 4 * k4);
            float4 h1 = *(const float4*)(h + (size_t)(r0 + 1) * KDIM + 4 * k4);
            float4 h2 = *(const float4*)(h + (size_t)(r0 + 2) * KDIM + 4 * k4);
            float4 h3 = *(const float4*)(h + (size_t)(r0 + 3) * KDIM + 4 * k4);
            acc0 = fmaf(h0.x, w0, acc0); acc0 = fmaf(h0.y, w1, acc0);
            acc0 = fmaf(h0.z, w2, acc0); acc0 = fmaf(h0.w, w3, acc0);
            acc1 = fmaf(h1.x, w0, acc1); acc1 = fmaf(h1.y, w1, acc1);
            acc1 = fmaf(h1.z, w2, acc1); acc1 = fmaf(h1.w, w3, acc1);
            acc2 = fmaf(h2.x, w0, acc2); acc2 = fmaf(h2.y, w1, acc2);
            acc2 = fmaf(h2.z, w2, acc2); acc2 = fmaf(h2.w, w3, acc2);
            acc3 = fmaf(h3.x, w0, acc3); acc3 = fmaf(h3.y, w1, acc3);
            acc3 = fmaf(h3.z, w2, acc3); acc3 = fmaf(h3.w, w3, acc3);
        }
        myrow[0] = acc0; myrow[1] = acc1; myrow[2] = acc2; myrow[3] = acc3;
        float a1 = a[lane], a2 = a[DD + lane];
        #pragma unroll
        for (int i = 0; i < 4; ++i) {
            float r1 = myrow[i] * a1, r2 = myrow[i] * a2;
            #pragma unroll
            for (int off = 32; off > 0; off >>= 1) {
                r1 += __shfl_xor(r1, off, 64);
                r2 += __shfl_xor(r2, off, 64);
            }
            if (lane == 0) {
                cstf(&Wh2g[r0 + i], r2);
                ls_wh1[wv * 4 + i] = r1;
                ls_wh2[wv * 4 + i] = r2;
            }
        }
    }
    gridbar(flags, rel, 1);

    // ================= P1: redundant minmax+hist+scan (LDS) + scatter =================
    for (int i = t; i < NB; i += NTHR) ls_bstart[i] = 0;
    float v16[16];
    #pragma unroll
    for (int q = 0; q < 16; ++q)                    // batch-issue 16 bypass loads
        v16[q] = cldf(&Wh2g[t + q * NTHR]);
    {
        unsigned lmin = 0xFFFFFFFFu, lmax = 0u;
        #pragma unroll
        for (int q = 0; q < 16; ++q) {
            unsigned k = f2k(v16[q]);
            lmin = min(lmin, k); lmax = max(lmax, k);
        }
        #pragma unroll
        for (int off = 32; off > 0; off >>= 1) {
            lmin = min(lmin, (unsigned)__shfl_xor((int)lmin, off, 64));
            lmax = max(lmax, (unsigned)__shfl_xor((int)lmax, off, 64));
        }
        if (lane == 0) { ls_ra[wv] = lmin; ls_rb[wv] = lmax; }
    }
    __syncthreads();
    if (t == 0) {
        unsigned mn = ls_ra[0], mx = ls_rb[0];
        for (int i = 1; i < 8; ++i) { mn = min(mn, ls_ra[i]); mx = max(mx, ls_rb[i]); }
        ls_kmin = mn;
        ls_scale = (float)NB / ((float)(mx - mn) + 1.0f);
        ls_M2 = k2f(mx);
    }
    __syncthreads();
    const unsigned kmin = ls_kmin;
    const float scale = ls_scale;
    const float M2 = ls_M2;

    #pragma unroll
    for (int q = 0; q < 16; ++q)
        atomicAdd(&ls_bstart[bucket_of(f2k(v16[q]), kmin, scale)], 1);
    __syncthreads();
    {
        int s[8]; int tot = 0;
        #pragma unroll
        for (int j = 0; j < 8; ++j) { s[j] = ls_bstart[8 * t + j]; tot += s[j]; }
        int x = tot;
        #pragma unroll
        for (int off = 1; off < 64; off <<= 1) {
            int y = __shfl_up(x, off, 64);
            if (lane >= off) x += y;
        }
        if (lane == 63) ls_wsum[wv] = x;
        __syncthreads();
        int woff = 0;
        for (int w2 = 0; w2 < wv; ++w2) woff += ls_wsum[w2];
        int acc = woff + x - tot;
        #pragma unroll
        for (int j = 0; j < 8; ++j) { ls_bstart[8 * t + j] = acc; acc += s[j]; }
        if (t == 0) ls_bstart[NB] = NN;
    }
    __syncthreads();
    // scatter: lanes 0-3 issue the 4 cursor RMWs concurrently; packed svp stores
    {
        int posl = 0;
        if (lane < 4) {
            unsigned b = bucket_of(f2k(ls_wh2[wv * 4 + lane]), kmin, scale);
            posl = ls_bstart[b] + atomicAdd(&cnt[b], 1);
        }
        #pragma unroll
        for (int i = 0; i < 4; ++i) {
            int lr = wv * 4 + i;
            float x = ls_wh2[lr];
            int pos = __shfl(posl, i, 64);
            cstf(&sg[(size_t)pos * DD + lane], myrow[i]);
            if (lane == 0) {
                cstf2(&svp[4 * pos + 0], x, expf(LRALPHA * (x - M2)));   // sv, wn
                cstf2(&svp[4 * pos + 2], expf(x - M2), 0.f);             // wp, pad
            }
        }
    }
    gridbar(flags, rel, 2);

    // ================= P2: chunk sums + LDS stash of own chunk =================
    {
        int base = bid * CH + wv * 4;
        float g4[4]; float2 q01[4], q23[4];
        #pragma unroll
        for (int kk = 0; kk < 4; ++kk) {            // batch-issue 12 bypass loads
            int k = base + kk;
            g4[kk]  = cldf(&sg[(size_t)k * DD + lane]);
            q01[kk] = cldf2(&svp[4 * k + 0]);       // sv, wn
            q23[kk] = cldf2(&svp[4 * k + 2]);       // wp, pad
        }
        float an = 0.f, ap = 0.f, sn = 0.f, sp = 0.f;
        #pragma unroll
        for (int kk = 0; kk < 4; ++kk) {
            float wn = q01[kk].y, wp = q23[kk].x;
            an = fmaf(wn, g4[kk], an); ap = fmaf(wp, g4[kk], ap);
            sn += wn; sp += wp;
            ls_g[wv * 4 + kk][lane] = g4[kk];       // stash for P4
            if (lane == 0) { ls_wn[wv * 4 + kk] = wn; ls_wp[wv * 4 + kk] = wp; }
        }
        ls_cs[wv][lane] = an; ls_cs[wv][DD + lane] = ap;
        if (lane == 0) { ls_css[wv] = sn; ls_css[8 + wv] = sp; }
        __syncthreads();
        if (wv == 0) {
            float s = 0.f;
            #pragma unroll
            for (int w2 = 0; w2 < 8; ++w2) s += ls_cs[w2][lane];
            cstf(&cs_neg[bid * DD + lane], s);
            if (lane == 0) { float ss = 0.f; for (int w2 = 0; w2 < 8; ++w2) ss += ls_css[w2]; cstf(&cs_sn[bid], ss); }
        } else if (wv == 1) {
            float s = 0.f;
            #pragma unroll
            for (int w2 = 0; w2 < 8; ++w2) s += ls_cs[w2][DD + lane];
            cstf(&cs_pos[bid * DD + lane], s);
            if (lane == 0) { float ss = 0.f; for (int w2 = 0; w2 < 8; ++w2) ss += ls_css[8 + w2]; cstf(&cs_sp[bid], ss); }
        }
    }
    gridbar(flags, rel, 3);

    // ================= P3: blocks 0-2 scan the 256 chunk sums =================
    if (bid == 0) {
        const int c0 = wv * 32;
        float v[32];
        #pragma unroll
        for (int j = 0; j < 32; ++j) v[j] = cldf(&cs_neg[(c0 + j) * DD + lane]);
        float tot = 0.f;
        #pragma unroll
        for (int j = 0; j < 32; ++j) tot += v[j];
        ls_cs[wv][lane] = tot;
        __syncthreads();
        float acc = 0.f;
        for (int w2 = 0; w2 < wv; ++w2) acc += ls_cs[w2][lane];
        #pragma unroll
        for (int j = 0; j < 32; ++j) { cstf(&PN[(c0 + j) * DD + lane], acc); acc += v[j]; }
        if (wv == 7) cstf(&PN[NCH * DD + lane], acc);
    } else if (bid == 1) {
        const int c0 = wv * 32;
        float v[32];
        #pragma unroll
        for (int j = 0; j < 32; ++j) v[j] = cldf(&cs_pos[(c0 + j) * DD + lane]);
        float tot = 0.f;
        #pragma unroll
        for (int j = 0; j < 32; ++j) tot += v[j];
        ls_cs[wv][lane] = tot;
        __syncthreads();
        float acc = 0.f;
        for (int w2 = wv + 1; w2 < 8; ++w2) acc += ls_cs[w2][lane];
        #pragma unroll
        for (int j = 31; j >= 0; --j) { acc += v[j]; cstf(&SP[(c0 + j) * DD + lane], acc); }
        if (wv == 7) cstf(&SP[NCH * DD + lane], 0.f);
    } else if (bid == 2) {
        if (wv == 0) {          // scalar prefix
            float s[4];
            #pragma unroll
            for (int j = 0; j < 4; ++j) s[j] = cldf(&cs_sn[4 * lane + j]);
            float tot = s[0] + s[1] + s[2] + s[3];
            float x = tot;
            #pragma unroll
            for (int off = 1; off < 64; off <<= 1) {
                float y = __shfl_up(x, off, 64);
                if (lane >= off) x += y;
            }
            float acc = x - tot;
            #pragma unroll
            for (int j = 0; j < 4; ++j) { cstf(&PNs[4 * lane + j], acc); acc += s[j]; }
            if (lane == 63) cstf(&PNs[NCH], acc);
        } else if (wv == 1) {   // scalar suffix
            float s[4];
            #pragma unroll
            for (int j = 0; j < 4; ++j) s[j] = cldf(&cs_sp[4 * lane + j]);
            float tot = s[0] + s[1] + s[2] + s[3];
            float x = tot;
            #pragma unroll
            for (int off = 1; off < 64; off <<= 1) {
                float y = __shfl_down(x, off, 64);
                if (lane < 64 - off) x += y;
            }
            float acc = x - tot;   // sum over lanes > lane
            #pragma unroll
            for (int j = 3; j >= 0; --j) { acc += s[j]; cstf(&SPs[4 * lane + j], acc); }
            if (lane == 63) cstf(&SPs[NCH], 0.f);
        }
    }
    gridbar(flags, rel, 4);

    // ================= P4: per-element prefix/suffix write for own chunk =============
    // wave 0: exclusive prefix of wn*g; wave 1: inclusive suffix of wp*g (from LDS stash)
    if (wv == 0) {
        float accn  = cldf(&PN[bid * DD + lane]);   // sum over chunks < bid
        float accns = cldf(&PNs[bid]);
        for (int k = 0; k < CH; ++k) {
            int e = bid * CH + k;
            cstf(&PNe[(size_t)e * DD + lane], accn);
            if (lane == 0) cstf(&PNse[e], accns);
            float wn = ls_wn[k], g = ls_g[k][lane];
            accn = fmaf(wn, g, accn); accns += wn;
        }
        if (bid == NBLK - 1) {
            cstf(&PNe[(size_t)NN * DD + lane], accn);
            if (lane == 0) cstf(&PNse[NN], accns);
        }
    } else if (wv == 1) {
        float accp  = cldf(&SP[(bid + 1) * DD + lane]);  // sum over chunks > bid
        float accps = cldf(&SPs[bid + 1]);
        for (int k = CH - 1; k >= 0; --k) {
            int e = bid * CH + k;
            float wp = ls_wp[k], g = ls_g[k][lane];
            accp = fmaf(wp, g, accp); accps += wp;
            cstf(&SPe[(size_t)e * DD + lane], accp);
            if (lane == 0) cstf(&SPse[e], accps);
        }
        if (bid == NBLK - 1) {
            cstf(&SPe[(size_t)NN * DD + lane], 0.f);
            if (lane == 0) cstf(&SPse[NN], 0.f);
        }
    }
    gridbar(flags, rel, 5);

    // ================= P5: output — exact headers + tiny in-bucket correction =========
    int p0a[4], p1a[4];
    #pragma unroll
    for (int i = 0; i < 4; ++i) {
        float tt = -ls_wh1[wv * 4 + i];
        unsigned kt = f2k(tt);
        int p0 = 0, p1 = 0;
        if (kt >= kmin) {
            unsigned b = bucket_of(kt, kmin, scale);
            p0 = ls_bstart[b]; p1 = ls_bstart[b + 1];
        }
        p0a[i] = p0; p1a[i] = p1;
    }
    float pn4[4], sp4[4], pns4[4], sps4[4];
    #pragma unroll
    for (int i = 0; i < 4; ++i) {                   // batch-issue 16 header loads
        pn4[i]  = cldf(&PNe[(size_t)p0a[i] * DD + lane]);
        sp4[i]  = cldf(&SPe[(size_t)p1a[i] * DD + lane]);
        pns4[i] = cldf(&PNse[p0a[i]]);
        sps4[i] = cldf(&SPse[p1a[i]]);
    }
    #pragma unroll
    for (int i = 0; i < 4; ++i) {
        int row = rowBase + wv * 4 + i;
        float w1 = ls_wh1[wv * 4 + i];
        float z = w1 + M2;                          // max_j (Wh1_i + Wh2_j)
        float m = (z >= 0.f) ? z : LRALPHA * z;     // lrelu(z) = exact row max
        float c1 = expf(z - m);                     // exponent <= 0
        float c2 = expf(LRALPHA * z - m);           // exponent <= 0
        float tt = -w1;
        float nn_ = pn4[i], dn_ = pns4[i];
        float np_ = sp4[i], dp_ = sps4[i];
        // in-bucket correction: avg ~2 elements, batched 4-wide with clamped loads
        int p0 = p0a[i], p1 = p1a[i];
        for (int k0 = p0; k0 < p1; k0 += 4) {
            float2 q01[4], q23[4]; float g4[4];
            #pragma unroll
            for (int j = 0; j < 4; ++j) {           // batch-issue 12 loads (clamped)
                int k = (k0 + j < p1) ? (k0 + j) : (p1 - 1);
                q01[j] = cldf2(&svp[4 * k + 0]);
                q23[j] = cldf2(&svp[4 * k + 2]);
                g4[j]  = cldf(&sg[(size_t)k * DD + lane]);
            }
            #pragma unroll
            for (int j = 0; j < 4; ++j) {
                if (k0 + j < p1) {
                    float svv = q01[j].x, wn = q01[j].y, wp = q23[j].x, g = g4[j];
                    if (svv <= tt) { nn_ = fmaf(wn, g, nn_); dn_ += wn; }
                    else           { np_ = fmaf(wp, g, np_); dp_ += wp; }
                }
            }
        }
        float num = c2 * nn_ + c1 * np_;
        float den = c2 * dn_ + c1 * dp_;
        float r = num / den;
        out[(size_t)row * DD + lane] = (r > 0.f) ? r : expm1f(r);   // elu
    }
}

extern "C" void kernel_launch(void* const* d_in, const int* in_sizes, int n_in,
                              void* d_out, int out_size, void* d_ws, size_t ws_size,
                              hipStream_t stream)
{
    const float* h = (const float*)d_in[0];
    // d_in[1] = adj (bool, unused by the reference computation)
    const float* W = (const float*)d_in[2];
    const float* a = (const float*)d_in[3];
    float* out = (float*)d_out;
    float* ws = (float*)d_ws;

    float* Wh2g   = ws;                              // NN
    float* svp    = Wh2g + NN;                       // 4*NN (sv, wn, wp, pad)
    float* sg     = svp + 4 * NN;                    // NN*DD (sorted Wh rows)
    float* cs_neg = sg + (size_t)NN * DD;            // NCH*DD
    float* cs_pos = cs_neg + NCH * DD;               // NCH*DD
    float* cs_sn  = cs_pos + NCH * DD;               // NCH
    float* cs_sp  = cs_sn + NCH;                     // NCH
    float* PN     = cs_sp + NCH;                     // (NCH+1)*DD chunk headers
    float* SP     = PN + (NCH + 1) * DD;             // (NCH+1)*DD
    float* PNs    = SP + (NCH + 1) * DD;             // NCH+1 (pad 320)
    float* SPs    = PNs + 320;                       // NCH+1 (pad 320)
    float* PNe    = SPs + 320;                       // (NN+1)*DD per-element prefix
    float* SPe    = PNe + (size_t)(NN + 1) * DD;     // (NN+1)*DD per-element suffix
    float* PNse   = SPe + (size_t)(NN + 1) * DD;     // NN+1 (pad NN+64)
    float* SPse   = PNse + (NN + 64);                // NN+1 (pad NN+64)
    unsigned* flags = (unsigned*)(SPse + (NN + 64)); // NBLK
    unsigned* rel   = flags + NBLK;                  // 1 (+pad to 256)
    int*   cnt    = (int*)(rel + 256);               // NB cursors (must start at 0)

    // zero flags + rel + cnt in one captured async memset
    hipMemsetAsync(flags, 0, (NBLK + 256 + NB) * sizeof(unsigned), stream);
    k_fused<<<NBLK, NTHR, 0, stream>>>(h, W, a, out,
        Wh2g, svp, sg,
        cs_neg, cs_pos, cs_sn, cs_sp,
        PN, SP, PNs, SPs,
        PNe, SPe, PNse, SPse,
        cnt, flags, rel);
}